// Round 1
// baseline (125.048 us; speedup 1.0000x reference)
//
#include <hip/hip_runtime.h>
#include <hip/hip_bf16.h>
#include <stdint.h>

#define N_PTS   4096
#define M_CODES 4096
#define ZDIM    1024
#define BM 128
#define BN 128
#define BK 32

typedef __attribute__((ext_vector_type(8))) short bf16x8;
typedef __attribute__((ext_vector_type(4))) float f32x4;

__device__ __forceinline__ unsigned short f2bf(float f) {
    __hip_bfloat16 h = __float2bfloat16(f);
    return *reinterpret_cast<unsigned short*>(&h);
}

// order-preserving float -> uint map (monotone): enables atomicMin on uint
__device__ __forceinline__ unsigned enc_f32(float f) {
    unsigned u = __float_as_uint(f);
    return (u & 0x80000000u) ? ~u : (u | 0x80000000u);
}
__device__ __forceinline__ float dec_f32(unsigned e) {
    unsigned u = (e & 0x80000000u) ? (e ^ 0x80000000u) : ~e;
    return __uint_as_float(u);
}

// ---------------------------------------------------------------------------
// prep: fp32 -> bf16 cast of z and e, row sum-of-squares, min-array init.
// grid = 8192 blocks (4096 z rows then 4096 e rows), 256 threads.
// ---------------------------------------------------------------------------
__global__ __launch_bounds__(256) void prep_kernel(
    const float* __restrict__ z, const float* __restrict__ e,
    unsigned short* __restrict__ zb, unsigned short* __restrict__ eb,
    float* __restrict__ zsq, float* __restrict__ esq,
    unsigned* __restrict__ min_enc) {
    const int row = blockIdx.x;
    const int t = threadIdx.x;
    if (row < 16) min_enc[row * 256 + t] = 0xFFFFFFFFu;  // +inf-ish encoding

    const float* src;
    unsigned short* dst;
    float* sqp;
    if (row < N_PTS) {
        src = z + (size_t)row * ZDIM; dst = zb + (size_t)row * ZDIM; sqp = zsq + row;
    } else {
        const int r = row - N_PTS;
        src = e + (size_t)r * ZDIM; dst = eb + (size_t)r * ZDIM; sqp = esq + r;
    }
    float4 v = reinterpret_cast<const float4*>(src)[t];  // 256*4 = 1024 elems
    ushort4 o;
    o.x = f2bf(v.x); o.y = f2bf(v.y); o.z = f2bf(v.z); o.w = f2bf(v.w);
    reinterpret_cast<ushort4*>(dst)[t] = o;
    float s = v.x * v.x + v.y * v.y + v.z * v.z + v.w * v.w;
    #pragma unroll
    for (int off = 32; off > 0; off >>= 1) s += __shfl_down(s, off, 64);
    __shared__ float red[4];
    if ((t & 63) == 0) red[t >> 6] = s;
    __syncthreads();
    if (t == 0) *sqp = red[0] + red[1] + red[2] + red[3];
}

// ---------------------------------------------------------------------------
// gemm_min: 128x128x32 bf16 MFMA tile (m97 pattern), fused column-min epilogue.
// C[i][j] = z[i].e[j]; we track per-code-j: min_i (zsq[i] - 2*C[i][j]).
// grid = (M_CODES/BN, N_PTS/BM), 256 threads = 4 waves (2x2 of 64x64).
// ---------------------------------------------------------------------------
__global__ __launch_bounds__(256) void gemm_min_kernel(
    const unsigned short* __restrict__ zb, const unsigned short* __restrict__ eb,
    const float* __restrict__ zsq, unsigned* __restrict__ min_enc) {
    __shared__ __align__(16) unsigned short As[BM * BK];  // 8 KB, row-major [128][32], no pad
    __shared__ __align__(16) unsigned short Bs[BN * BK];  // 8 KB
    __shared__ float zsq_s[BM];

    const int t = threadIdx.x;
    const int bx = blockIdx.x;  // code (col) block
    const int by = blockIdx.y;  // point (row) block
    const int lane = t & 63;
    const int w = t >> 6;
    const int wm = w >> 1, wn = w & 1;
    const int lrow = lane & 15;
    const int q = lane >> 4;

    if (t < BM) zsq_s[t] = zsq[by * BM + t];

    f32x4 acc[4][4];
    #pragma unroll
    for (int i = 0; i < 4; i++)
        #pragma unroll
        for (int j = 0; j < 4; j++) acc[i][j] = (f32x4){0.f, 0.f, 0.f, 0.f};

    // staging geometry: thread t covers bytes [t*16, t*16+16) of the 8 KB tile
    // (instr 0), and the same +4096 B (instr 1). Tile row = 64 B.
    const int row0 = (t * 16) >> 6;         // 0..63
    const int kel0 = ((t * 16) & 63) >> 1;  // k-element offset 0/8/16/24
    const int lds_b0 = (t >> 6) * 512;      // wave-uniform LDS base (elements)
    const size_t a_base = (size_t)(by * BM) * ZDIM;
    const size_t b_base = (size_t)(bx * BN) * ZDIM;

    for (int k0 = 0; k0 < ZDIM; k0 += BK) {
        const unsigned short* ga0 = zb + a_base + (size_t)row0 * ZDIM + k0 + kel0;
        const unsigned short* gb0 = eb + b_base + (size_t)row0 * ZDIM + k0 + kel0;
        __builtin_amdgcn_global_load_lds(
            (const __attribute__((address_space(1))) void*)ga0,
            (__attribute__((address_space(3))) void*)(As + lds_b0), 16, 0, 0);
        __builtin_amdgcn_global_load_lds(
            (const __attribute__((address_space(1))) void*)(ga0 + (size_t)64 * ZDIM),
            (__attribute__((address_space(3))) void*)(As + 2048 + lds_b0), 16, 0, 0);
        __builtin_amdgcn_global_load_lds(
            (const __attribute__((address_space(1))) void*)gb0,
            (__attribute__((address_space(3))) void*)(Bs + lds_b0), 16, 0, 0);
        __builtin_amdgcn_global_load_lds(
            (const __attribute__((address_space(1))) void*)(gb0 + (size_t)64 * ZDIM),
            (__attribute__((address_space(3))) void*)(Bs + 2048 + lds_b0), 16, 0, 0);
        __syncthreads();

        bf16x8 a[4], b[4];
        #pragma unroll
        for (int am = 0; am < 4; am++)
            a[am] = *(const bf16x8*)(As + (wm * 64 + am * 16 + lrow) * BK + q * 8);
        #pragma unroll
        for (int an = 0; an < 4; an++)
            b[an] = *(const bf16x8*)(Bs + (wn * 64 + an * 16 + lrow) * BK + q * 8);
        #pragma unroll
        for (int am = 0; am < 4; am++)
            #pragma unroll
            for (int an = 0; an < 4; an++)
                acc[am][an] = __builtin_amdgcn_mfma_f32_16x16x32_bf16(
                    a[am], b[an], acc[am][an], 0, 0, 0);
        __syncthreads();
    }

    // Epilogue: per-lane min over (am, reg), then cross-lane over q-groups,
    // then device atomicMin per column. C/D layout: row = q*4+r, col = lrow.
    #pragma unroll
    for (int an = 0; an < 4; an++) {
        float v = 3.4e38f;
        #pragma unroll
        for (int am = 0; am < 4; am++) {
            const int rbase = wm * 64 + am * 16 + q * 4;
            f32x4 c = acc[am][an];
            v = fminf(v, zsq_s[rbase + 0] - 2.f * c[0]);
            v = fminf(v, zsq_s[rbase + 1] - 2.f * c[1]);
            v = fminf(v, zsq_s[rbase + 2] - 2.f * c[2]);
            v = fminf(v, zsq_s[rbase + 3] - 2.f * c[3]);
        }
        v = fminf(v, __shfl_xor(v, 16, 64));
        v = fminf(v, __shfl_xor(v, 32, 64));
        if (q == 0) {
            const int col = bx * BN + wn * 64 + an * 16 + lrow;
            atomicMin(&min_enc[col], enc_f32(v));
        }
    }
}

// ---------------------------------------------------------------------------
// finalize: mean_j (dec(min_enc[j]) + esq[j]) -> single fp32 scalar.
// ---------------------------------------------------------------------------
__global__ __launch_bounds__(256) void finalize_kernel(
    const unsigned* __restrict__ min_enc, const float* __restrict__ esq,
    float* __restrict__ out) {
    const int t = threadIdx.x;
    float s = 0.f;
    #pragma unroll
    for (int i = 0; i < M_CODES / 256; i++) {
        const int j = i * 256 + t;
        s += dec_f32(min_enc[j]) + esq[j];
    }
    #pragma unroll
    for (int off = 32; off > 0; off >>= 1) s += __shfl_down(s, off, 64);
    __shared__ float red[4];
    if ((t & 63) == 0) red[t >> 6] = s;
    __syncthreads();
    if (t == 0) out[0] = (red[0] + red[1] + red[2] + red[3]) * (1.f / M_CODES);
}

extern "C" void kernel_launch(void* const* d_in, const int* in_sizes, int n_in,
                              void* d_out, int out_size, void* d_ws, size_t ws_size,
                              hipStream_t stream) {
    (void)in_sizes; (void)n_in; (void)out_size; (void)ws_size;
    const float* z = (const float*)d_in[0];
    const float* e = (const float*)d_in[1];
    char* ws = (char*)d_ws;
    unsigned short* zb = (unsigned short*)ws;                           // 8 MB
    unsigned short* eb = (unsigned short*)(ws + ((size_t)8 << 20));     // 8 MB
    float* zsq = (float*)(ws + ((size_t)16 << 20));                     // 16 KB
    float* esq = (float*)(ws + ((size_t)16 << 20) + 4096 * 4);          // 16 KB
    unsigned* min_enc = (unsigned*)(ws + ((size_t)16 << 20) + 2 * 4096 * 4);  // 16 KB

    prep_kernel<<<dim3(8192), dim3(256), 0, stream>>>(z, e, zb, eb, zsq, esq, min_enc);
    gemm_min_kernel<<<dim3(M_CODES / BN, N_PTS / BM), dim3(256), 0, stream>>>(
        zb, eb, zsq, min_enc);
    finalize_kernel<<<dim3(1), dim3(256), 0, stream>>>(min_enc, esq, (float*)d_out);
}